// Round 8
// baseline (644.351 us; speedup 1.0000x reference)
//
#include <hip/hip_runtime.h>

#define NB 8
#define NC 256          // K
#define IMG 3600
#define MP 3584         // M padded (multiple of 128)
#define SCALE 0.28853901f   // 0.2 * log2(e): exp(0.2*dot) = exp2(SCALE*dot)
#define LN2X2 1.38629436f   // 2*ln2: dist_diag = ln2 * acc'

typedef unsigned short u16;
typedef __bf16 bf16x8 __attribute__((ext_vector_type(8)));
typedef float  f32x4  __attribute__((ext_vector_type(4)));
typedef unsigned short u16x8 __attribute__((ext_vector_type(8)));

#if __has_builtin(__builtin_amdgcn_exp2f)
#define EXP2(x) __builtin_amdgcn_exp2f(x)
#else
#define EXP2(x) exp2f(x)
#endif

__device__ __forceinline__ u16 f2bf(float f) {
  unsigned u = __builtin_bit_cast(unsigned, f);
  u += 0x7FFFu + ((u >> 16) & 1u);          // round-to-nearest-even
  return (u16)(u >> 16);
}

// ---------------------------------------------------------------------------
// B gather + cast, k-chunk-major: des2 chunk (b,kc,m) = p2[b][kc*8+j][pix2(m)]
// at ((b*32+kc)*MP + m)*8 u16. Rows >= M zero-filled. NO scale (A carries it).
// ---------------------------------------------------------------------------
__global__ __launch_bounds__(256)
void gather_b(const float* __restrict__ p2,
              const int* __restrict__ y2, const int* __restrict__ x2,
              u16* __restrict__ des2, int M) {
  const int b = blockIdx.z;
  const int t = threadIdx.x;
  const int row_l = t & 63;
  const int kc0 = (blockIdx.y * 4 + (t >> 6)) * 2;   // 2 chunks per thread
  const int m = blockIdx.x * 64 + row_l;
  const bool mv = m < M;
  const int pix = mv ? (y2[m] * 60 + x2[m]) : 0;
  const float* src = p2 + ((size_t)b * NC + kc0 * 8) * IMG + pix;

#pragma unroll
  for (int c = 0; c < 2; ++c) {
    u16x8 h;
#pragma unroll
    for (int j = 0; j < 8; ++j) {
      float v = mv ? src[(size_t)(c * 8 + j) * IMG] : 0.f;
      h[j] = f2bf(v);
    }
    *(u16x8*)(des2 + (((size_t)b * 32 + kc0 + c) * MP + m) * 8) = h;
  }
}

// ---------------------------------------------------------------------------
// Fused A-gather + MFMA GEMM + exp2 + row/col/diag.
// Block = (batch b, 128 A-rows mt, col-group grp of 28 strips); grid 896.
// Phase 1: gather A rows from p1 (scaled by 0.2*log2e, bf16) into LDS
//   [kc][row] (64 KB), ONE __syncthreads. Phase 2 (barrier-free): each of
//   4 waves sweeps 7 disjoint 32-col strips; B frags (k-chunk-major global,
//   coalesced 256B segments) ping-pong prefetched half-K ahead; 128 MFMAs
//   + 64 bare v_exp per strip. NO per-element masking: pad rows/cols are
//   zero -> exp2(0)=1, corrected by exact constant in finalize.
// Frag layouts (16x16x32 bf16): A/B[row=l15][k=quad*8+j]; C/D col=l15,
// row=quad*4+reg.  batch = blockIdx&7 -> XCD-pinned L2 working set.
// ---------------------------------------------------------------------------
__global__ __launch_bounds__(256, 2)
void mfma_lse(const float* __restrict__ p1,
              const int* __restrict__ y1, const int* __restrict__ x1,
              const u16* __restrict__ des2,
              float* __restrict__ row_sum, float* __restrict__ col_sum,
              float* __restrict__ diag, int M) {
  __shared__ __align__(16) u16 Asl[32 * 128 * 8];   // [kc][row] 16B chunks, 64 KB

  const int flat = blockIdx.x;
  const int b = flat & 7;
  const int f = flat >> 3;          // 0..111
  const int mt = f % 28;
  const int grp = f / 28;           // 0..3, 28 strips each
  const int m0 = mt * 128;
  const int t = threadIdx.x;
  const int w = t >> 6, lane = t & 63;
  const int quad = lane >> 4, l15 = lane & 15;

  const u16* D2b = des2 + (size_t)b * 32 * MP * 8;

  auto strip_of = [&](int jj) { return grp * 28 + w + 4 * ((jj + mt) % 7); };

  bf16x8 b0[2][4], b1[2][4];
  auto loadB = [&](bf16x8 (&dst)[2][4], int s, int h) {
#pragma unroll
    for (int jn = 0; jn < 2; ++jn)
#pragma unroll
      for (int ss = 0; ss < 4; ++ss) {
        const int kc = h * 16 + ss * 4 + quad;
        dst[jn][ss] = *(const bf16x8*)(
            D2b + ((size_t)kc * MP + s * 32 + jn * 16 + l15) * 8);
      }
  };

  loadB(b0, strip_of(0), 0);   // in flight across the A-gather

  // ---- Phase 1: inline A gather -> LDS (scaled bf16) ----
  {
    const int row128 = t & 127, chalf = t >> 7;
    const int m = m0 + row128;
    const bool mv = m < M;
    const int pix = mv ? (y1[m] * 60 + x1[m]) : 0;
    const float* srcA = p1 + (size_t)b * NC * IMG + pix;
#pragma unroll
    for (int c8 = 0; c8 < 16; ++c8) {
      const int kc = chalf * 16 + c8;
      u16x8 h;
#pragma unroll
      for (int j = 0; j < 8; ++j) {
        float v = mv ? srcA[(size_t)(kc * 8 + j) * IMG] : 0.f;
        h[j] = f2bf(v * SCALE);
      }
      *(u16x8*)&Asl[((size_t)kc * 128 + row128) * 8] = h;
    }
  }
  __syncthreads();               // the ONLY barrier

  float rowReg[32];
#pragma unroll
  for (int i = 0; i < 32; ++i) rowReg[i] = 0.f;

  for (int jj = 0; jj < 7; ++jj) {
    const int s = strip_of(jj);
    f32x4 acc[8][2] = {};

    loadB(b1, s, 1);             // half-K 1 of current strip

    auto do_half = [&](bf16x8 (&B)[2][4], int h) {
#pragma unroll
      for (int ss = 0; ss < 4; ++ss) {
        const int kc = (h * 4 + ss) * 4 + quad;
#pragma unroll
        for (int it = 0; it < 8; ++it) {
          bf16x8 a = *(const bf16x8*)&Asl[((size_t)kc * 128 + it * 16 + l15) * 8];
          acc[it][0] = __builtin_amdgcn_mfma_f32_16x16x32_bf16(
              a, B[0][ss], acc[it][0], 0, 0, 0);
          acc[it][1] = __builtin_amdgcn_mfma_f32_16x16x32_bf16(
              a, B[1][ss], acc[it][1], 0, 0, 0);
        }
      }
    };

    do_half(b0, 0);
    if (jj + 1 < 7) loadB(b0, strip_of(jj + 1), 0);   // next strip half-K 0
    do_half(b1, 1);

    // ---- lean epilogue: bare exp2, no masks ----
    float cp0 = 0.f, cp1 = 0.f;
#pragma unroll
    for (int it = 0; it < 8; ++it)
#pragma unroll
      for (int r = 0; r < 4; ++r) {
        float e0 = EXP2(acc[it][0][r]);
        float e1 = EXP2(acc[it][1][r]);
        rowReg[it * 4 + r] += e0 + e1;
        cp0 += e0;
        cp1 += e1;
      }
    cp0 += __shfl_xor(cp0, 16); cp0 += __shfl_xor(cp0, 32);
    cp1 += __shfl_xor(cp1, 16); cp1 += __shfl_xor(cp1, 32);
    if (quad == 0) {
      atomicAdd(&col_sum[(size_t)b * MP + s * 32 + l15], cp0);
      atomicAdd(&col_sum[(size_t)b * MP + s * 32 + 16 + l15], cp1);
    }

    if ((s >> 2) == mt) {        // this strip holds the diagonal
#pragma unroll
      for (int jn = 0; jn < 2; ++jn) {
        const int it = 2 * w + jn;
#pragma unroll
        for (int r = 0; r < 4; ++r)
          if (l15 == quad * 4 + r)
            diag[(size_t)b * MP + m0 + it * 16 + quad * 4 + r] = acc[it][jn][r];
      }
    }
  }

  // ---- row sums: reduce over this wave's 16 cols (l15), one atomic each ----
#pragma unroll
  for (int it = 0; it < 8; ++it)
#pragma unroll
    for (int r = 0; r < 4; ++r) {
      float v = rowReg[it * 4 + r];
      v += __shfl_xor(v, 1); v += __shfl_xor(v, 2);
      v += __shfl_xor(v, 4); v += __shfl_xor(v, 8);
      if (l15 == 0)
        atomicAdd(&row_sum[(size_t)b * MP + m0 + it * 16 + quad * 4 + r], v);
    }
}

// ---------------------------------------------------------------------------
// loss = mean over valid of log(rs - pad) + log(cs - pad) - 2*ln2*diag'
// pad = MP - M exact (pad rows/cols contributed exp2(0)=1 each).
// ---------------------------------------------------------------------------
__global__ __launch_bounds__(256)
void finalize(const float* __restrict__ row_sum, const float* __restrict__ col_sum,
              const float* __restrict__ diag, float* __restrict__ out,
              int M, float padf, float inv_total) {
  __shared__ float red[4];
  const int i = blockIdx.x * 256 + threadIdx.x;   // over NB*MP
  const int mm = i % MP;
  float s = 0.f;
  if (mm < M)
    s = logf(row_sum[i] - padf) + logf(col_sum[i] - padf) - LN2X2 * diag[i];
#pragma unroll
  for (int o = 1; o < 64; o <<= 1) s += __shfl_xor(s, o);
  const int lane = threadIdx.x & 63, wid = threadIdx.x >> 6;
  if (lane == 0) red[wid] = s;
  __syncthreads();
  if (threadIdx.x == 0)
    atomicAdd(out, (red[0] + red[1] + red[2] + red[3]) * inv_total);
}

extern "C" void kernel_launch(void* const* d_in, const int* in_sizes, int n_in,
                              void* d_out, int out_size, void* d_ws, size_t ws_size,
                              hipStream_t stream) {
  const float* p1 = (const float*)d_in[0];
  const float* p2 = (const float*)d_in[1];
  const int* y1 = (const int*)d_in[2];
  const int* x1 = (const int*)d_in[3];
  const int* y2 = (const int*)d_in[4];
  const int* x2 = (const int*)d_in[5];
  const int M = in_sizes[2];                    // 3540 (<= MP)

  float* row_sum = (float*)d_ws;                // NB*MP
  float* col_sum = row_sum + (size_t)NB * MP;   // NB*MP
  float* diagbuf = col_sum + (size_t)NB * MP;   // NB*MP
  size_t off = (((size_t)3 * NB * MP * sizeof(float)) + 255) & ~(size_t)255;
  u16* des2 = (u16*)((char*)d_ws + off);        // NB*32 chunks * MP * 8 u16

  hipMemsetAsync(d_ws, 0, (size_t)2 * NB * MP * sizeof(float), stream);
  hipMemsetAsync(d_out, 0, sizeof(float), stream);

  dim3 ggrid(MP / 64, 4, NB);                   // (56, 4, 8)
  gather_b<<<ggrid, 256, 0, stream>>>(p2, y2, x2, des2, M);

  mfma_lse<<<dim3(NB * 28 * 4), 256, 0, stream>>>(p1, y1, x1, des2, row_sum,
                                                  col_sum, diagbuf, M);

  finalize<<<(NB * MP) / 256, 256, 0, stream>>>(row_sum, col_sum, diagbuf,
                                                (float*)d_out, M,
                                                (float)(MP - M),
                                                1.f / (float)(NB * M));
}

// Round 9
// 513.167 us; speedup vs baseline: 1.2556x; 1.2556x over previous
//
#include <hip/hip_runtime.h>

#define NB 8
#define NC 256          // K
#define IMG 3600
#define MP 3584         // M padded (multiple of 128)
#define SCALE 0.28853901f   // 0.2 * log2(e): exp(0.2*dot) = exp2(SCALE*dot)
#define LN2X2 1.38629436f   // 2*ln2: dist_diag = ln2 * acc'

typedef unsigned short u16;
typedef __bf16 bf16x8 __attribute__((ext_vector_type(8)));
typedef float  f32x4  __attribute__((ext_vector_type(4)));
typedef unsigned short u16x8 __attribute__((ext_vector_type(8)));

#define EXP2(x) exp2f(x)

__device__ __forceinline__ u16 f2bf(float f) {
  unsigned u = __builtin_bit_cast(unsigned, f);
  u += 0x7FFFu + ((u >> 16) & 1u);          // round-to-nearest-even
  return (u16)(u >> 16);
}

// ---------------------------------------------------------------------------
// B gather + cast, k-chunk-major: des2 chunk (b,kc,m) = p2[b][kc*8+j][pix2(m)]
// at ((b*32+kc)*MP + m)*8 u16. Rows >= M zero-filled. NO scale (A carries it).
// ---------------------------------------------------------------------------
__global__ __launch_bounds__(256)
void gather_b(const float* __restrict__ p2,
              const int* __restrict__ y2, const int* __restrict__ x2,
              u16* __restrict__ des2, int M) {
  const int b = blockIdx.z;
  const int t = threadIdx.x;
  const int row_l = t & 63;
  const int kc0 = (blockIdx.y * 4 + (t >> 6)) * 2;   // 2 chunks per thread
  const int m = blockIdx.x * 64 + row_l;
  const bool mv = m < M;
  const int pix = mv ? (y2[m] * 60 + x2[m]) : 0;
  const float* src = p2 + ((size_t)b * NC + kc0 * 8) * IMG + pix;

#pragma unroll
  for (int c = 0; c < 2; ++c) {
    u16x8 h;
#pragma unroll
    for (int j = 0; j < 8; ++j) {
      float v = mv ? src[(size_t)(c * 8 + j) * IMG] : 0.f;
      h[j] = f2bf(v);
    }
    *(u16x8*)(des2 + (((size_t)b * 32 + kc0 + c) * MP + m) * 8) = h;
  }
}

// ---------------------------------------------------------------------------
// Fused A-gather + MFMA GEMM + exp2 + row/col/diag.
// Block = (batch b, 128 A-rows mt, col-group grp of 28 strips); grid 896.
// Phase 1: gather A rows from p1 (scaled by 0.2*log2e, bf16) into LDS
//   [kc][row] (64 KB), ONE __syncthreads. Phase 2 (barrier-free): each of
//   4 waves sweeps 7 disjoint 32-col strips; B frags (k-chunk-major global,
//   coalesced 256B segments) ping-pong prefetched half-K ahead; 128 MFMAs
//   + 64 bare v_exp per strip. NO per-element masking: pad rows/cols are
//   zero -> exp2(0)=1, corrected by exact constant in finalize.
// NOTE: every subscript into acc[][]/b0/b1 must be COMPILE-TIME — a runtime
// index demotes the register array to scratch (R8: 1.3 GB spill traffic).
// Frag layouts (16x16x32 bf16): A/B[row=l15][k=quad*8+j]; C/D col=l15,
// row=quad*4+reg.  batch = blockIdx&7 -> XCD-pinned L2 working set.
// ---------------------------------------------------------------------------
__global__ __launch_bounds__(256, 2)
void mfma_lse(const float* __restrict__ p1,
              const int* __restrict__ y1, const int* __restrict__ x1,
              const u16* __restrict__ des2,
              float* __restrict__ row_sum, float* __restrict__ col_sum,
              float* __restrict__ diag, int M) {
  __shared__ __align__(16) u16 Asl[32 * 128 * 8];   // [kc][row] 16B chunks, 64 KB

  const int flat = blockIdx.x;
  const int b = flat & 7;
  const int f = flat >> 3;          // 0..111
  const int mt = f % 28;
  const int grp = f / 28;           // 0..3, 28 strips each
  const int m0 = mt * 128;
  const int t = threadIdx.x;
  const int w = t >> 6, lane = t & 63;
  const int quad = lane >> 4, l15 = lane & 15;

  const u16* D2b = des2 + (size_t)b * 32 * MP * 8;

  auto strip_of = [&](int jj) { return grp * 28 + w + 4 * ((jj + mt) % 7); };

  bf16x8 b0[2][4], b1[2][4];
  auto loadB = [&](bf16x8 (&dst)[2][4], int s, int h) {
#pragma unroll
    for (int jn = 0; jn < 2; ++jn)
#pragma unroll
      for (int ss = 0; ss < 4; ++ss) {
        const int kc = h * 16 + ss * 4 + quad;
        dst[jn][ss] = *(const bf16x8*)(
            D2b + ((size_t)kc * MP + s * 32 + jn * 16 + l15) * 8);
      }
  };

  loadB(b0, strip_of(0), 0);   // in flight across the A-gather

  // ---- Phase 1: inline A gather -> LDS (scaled bf16) ----
  {
    const int row128 = t & 127, chalf = t >> 7;
    const int m = m0 + row128;
    const bool mv = m < M;
    const int pix = mv ? (y1[m] * 60 + x1[m]) : 0;
    const float* srcA = p1 + (size_t)b * NC * IMG + pix;
#pragma unroll
    for (int c8 = 0; c8 < 16; ++c8) {
      const int kc = chalf * 16 + c8;
      u16x8 h;
#pragma unroll
      for (int j = 0; j < 8; ++j) {
        float v = mv ? srcA[(size_t)(kc * 8 + j) * IMG] : 0.f;
        h[j] = f2bf(v * SCALE);
      }
      *(u16x8*)&Asl[((size_t)kc * 128 + row128) * 8] = h;
    }
  }
  __syncthreads();               // the ONLY barrier

  float rowReg[32];
#pragma unroll
  for (int i = 0; i < 32; ++i) rowReg[i] = 0.f;

  for (int jj = 0; jj < 7; ++jj) {
    const int s = strip_of(jj);
    f32x4 acc[8][2] = {};

    loadB(b1, s, 1);             // half-K 1 of current strip

    auto do_half = [&](const bf16x8 (&B)[2][4], int h) {
#pragma unroll
      for (int ss = 0; ss < 4; ++ss) {
        const int kc = (h * 4 + ss) * 4 + quad;
#pragma unroll
        for (int it = 0; it < 8; ++it) {
          bf16x8 a = *(const bf16x8*)&Asl[((size_t)kc * 128 + it * 16 + l15) * 8];
          acc[it][0] = __builtin_amdgcn_mfma_f32_16x16x32_bf16(
              a, B[0][ss], acc[it][0], 0, 0, 0);
          acc[it][1] = __builtin_amdgcn_mfma_f32_16x16x32_bf16(
              a, B[1][ss], acc[it][1], 0, 0, 0);
        }
      }
    };

    do_half(b0, 0);
    if (jj + 1 < 7) loadB(b0, strip_of(jj + 1), 0);   // next strip half-K 0
    do_half(b1, 1);

    // ---- lean epilogue: bare exp2, no masks ----
    float cp0 = 0.f, cp1 = 0.f;
#pragma unroll
    for (int it = 0; it < 8; ++it)
#pragma unroll
      for (int r = 0; r < 4; ++r) {
        float e0 = EXP2(acc[it][0][r]);
        float e1 = EXP2(acc[it][1][r]);
        rowReg[it * 4 + r] += e0 + e1;
        cp0 += e0;
        cp1 += e1;
      }
    cp0 += __shfl_xor(cp0, 16); cp0 += __shfl_xor(cp0, 32);
    cp1 += __shfl_xor(cp1, 16); cp1 += __shfl_xor(cp1, 32);
    if (quad == 0) {
      atomicAdd(&col_sum[(size_t)b * MP + s * 32 + l15], cp0);
      atomicAdd(&col_sum[(size_t)b * MP + s * 32 + 16 + l15], cp1);
    }

    // diag: COMPILE-TIME indices only; runtime guard it == 2*w + jn.
    if ((s >> 2) == mt) {
#pragma unroll
      for (int it = 0; it < 8; ++it)
#pragma unroll
        for (int jn = 0; jn < 2; ++jn)
#pragma unroll
          for (int r = 0; r < 4; ++r)
            if (it == 2 * w + jn && l15 == quad * 4 + r)
              diag[(size_t)b * MP + m0 + it * 16 + quad * 4 + r] =
                  acc[it][jn][r];
    }
  }

  // ---- row sums: reduce over this wave's 16 cols (l15), one atomic each ----
#pragma unroll
  for (int it = 0; it < 8; ++it)
#pragma unroll
    for (int r = 0; r < 4; ++r) {
      float v = rowReg[it * 4 + r];
      v += __shfl_xor(v, 1); v += __shfl_xor(v, 2);
      v += __shfl_xor(v, 4); v += __shfl_xor(v, 8);
      if (l15 == 0)
        atomicAdd(&row_sum[(size_t)b * MP + m0 + it * 16 + quad * 4 + r], v);
    }
}

// ---------------------------------------------------------------------------
// loss = mean over valid of log(rs - pad) + log(cs - pad) - 2*ln2*diag'
// pad = MP - M exact (pad rows/cols contributed exp2(0)=1 each).
// ---------------------------------------------------------------------------
__global__ __launch_bounds__(256)
void finalize(const float* __restrict__ row_sum, const float* __restrict__ col_sum,
              const float* __restrict__ diag, float* __restrict__ out,
              int M, float padf, float inv_total) {
  __shared__ float red[4];
  const int i = blockIdx.x * 256 + threadIdx.x;   // over NB*MP
  const int mm = i % MP;
  float s = 0.f;
  if (mm < M)
    s = logf(row_sum[i] - padf) + logf(col_sum[i] - padf) - LN2X2 * diag[i];
#pragma unroll
  for (int o = 1; o < 64; o <<= 1) s += __shfl_xor(s, o);
  const int lane = threadIdx.x & 63, wid = threadIdx.x >> 6;
  if (lane == 0) red[wid] = s;
  __syncthreads();
  if (threadIdx.x == 0)
    atomicAdd(out, (red[0] + red[1] + red[2] + red[3]) * inv_total);
}

extern "C" void kernel_launch(void* const* d_in, const int* in_sizes, int n_in,
                              void* d_out, int out_size, void* d_ws, size_t ws_size,
                              hipStream_t stream) {
  const float* p1 = (const float*)d_in[0];
  const float* p2 = (const float*)d_in[1];
  const int* y1 = (const int*)d_in[2];
  const int* x1 = (const int*)d_in[3];
  const int* y2 = (const int*)d_in[4];
  const int* x2 = (const int*)d_in[5];
  const int M = in_sizes[2];                    // 3540 (<= MP)

  float* row_sum = (float*)d_ws;                // NB*MP
  float* col_sum = row_sum + (size_t)NB * MP;   // NB*MP
  float* diagbuf = col_sum + (size_t)NB * MP;   // NB*MP
  size_t off = (((size_t)3 * NB * MP * sizeof(float)) + 255) & ~(size_t)255;
  u16* des2 = (u16*)((char*)d_ws + off);        // NB*32 chunks * MP * 8 u16

  hipMemsetAsync(d_ws, 0, (size_t)2 * NB * MP * sizeof(float), stream);
  hipMemsetAsync(d_out, 0, sizeof(float), stream);

  dim3 ggrid(MP / 64, 4, NB);                   // (56, 4, 8)
  gather_b<<<ggrid, 256, 0, stream>>>(p2, y2, x2, des2, M);

  mfma_lse<<<dim3(NB * 28 * 4), 256, 0, stream>>>(p1, y1, x1, des2, row_sum,
                                                  col_sum, diagbuf, M);

  finalize<<<(NB * MP) / 256, 256, 0, stream>>>(row_sum, col_sum, diagbuf,
                                                (float*)d_out, M,
                                                (float)(MP - M),
                                                1.f / (float)(NB * M));
}

// Round 10
// 194.587 us; speedup vs baseline: 3.3114x; 2.6372x over previous
//
#include <hip/hip_runtime.h>

#define NB 8
#define NC 256          // K
#define IMG 3600
#define MP 3584         // M padded (multiple of 128)
#define NRB 28          // MP/128 row/col tiles
#define NKB 8           // NC/32 K-tiles of 32
#define SCALE 0.28853901f   // 0.2 * log2(e): exp(0.2*dot) = exp2(SCALE*dot)
#define LN2X2 1.38629436f   // 2*ln2: dist_diag term

typedef unsigned short u16;
typedef __bf16 bf16x8 __attribute__((ext_vector_type(8)));
typedef float  f32x4  __attribute__((ext_vector_type(4)));
typedef unsigned short u16x8 __attribute__((ext_vector_type(8)));

__device__ __forceinline__ u16 f2bf(float f) {
  unsigned u = __builtin_bit_cast(unsigned, f);
  u += 0x7FFFu + ((u >> 16) & 1u);          // round-to-nearest-even
  return (u16)(u >> 16);
}

__device__ __forceinline__ void gld16(const void* g, void* l) {
  __builtin_amdgcn_global_load_lds(
      (__attribute__((address_space(1))) void*)g,
      (__attribute__((address_space(3))) void*)l, 16, 0, 0);
}

// ---------------------------------------------------------------------------
// Gather + cast into 8-KB BK=32 tiles, bank-swizzled:
//   tile(b, kb, rb): 128 rows x 4 slots x 16B.  k-chunk ch of row m stored at
//   slot = ch ^ ((m>>1)&3)  ->  frag ds_read_b128 hits 8 banks x 2 lanes
//   (2-way aliasing = free).  A side (which==0) pre-scaled by SCALE.
//   Rows >= M zero-filled (pad correction applied exactly in finalize).
// ---------------------------------------------------------------------------
__global__ __launch_bounds__(256)
void gather_kernel(const float* __restrict__ p1, const float* __restrict__ p2,
                   const int* __restrict__ y1, const int* __restrict__ x1,
                   const int* __restrict__ y2, const int* __restrict__ x2,
                   u16* __restrict__ des1, u16* __restrict__ des2, int M) {
  const int which = blockIdx.z >> 3;       // 0 -> des1 (A), 1 -> des2 (B)
  const int b = blockIdx.z & 7;
  const float* P = (which ? p2 : p1) + (size_t)b * NC * IMG;
  const int* Y = which ? y2 : y1;
  const int* X = which ? x2 : x1;
  u16* D = which ? des2 : des1;

  const int t = threadIdx.x;
  const int row64 = t & 63;                // lane = row -> coalesced
  const int kc = blockIdx.y * 4 + (t >> 6); // global 16B k-chunk, 0..31
  const int m = blockIdx.x * 64 + row64;
  const bool mv = m < M;
  const int pix = mv ? (Y[m] * 60 + X[m]) : 0;
  const float* src = P + (size_t)(kc * 8) * IMG + pix;
  const float sc = which ? 1.f : SCALE;

  u16x8 h;
#pragma unroll
  for (int j = 0; j < 8; ++j) {
    float v = mv ? src[(size_t)j * IMG] : 0.f;
    h[j] = f2bf(v * sc);
  }
  const int kb = kc >> 2, ch = kc & 3;
  const int rb = m >> 7, row128 = m & 127;
  const int slot = ch ^ ((m >> 1) & 3);
  size_t idx = ((((size_t)b * NKB + kb) * NRB + rb) * 128 + row128) * 4 + slot;
  *(u16x8*)(D + idx * 8) = h;
}

// ---------------------------------------------------------------------------
// MFMA GEMM + fused exp2 / row / col / diag.   128x128 C-tile per block.
// LDS: double-buffered (A 8 KB + B 8 KB) x 2 = 32 KB -> VGPR-limited
// 3 blocks/CU (12 waves, 3/SIMD) for stall hiding. K-loop: 8 iters of BK=32;
// stage kb+1 (4 gld16/thread), s_waitcnt vmcnt(4) (waits kb only), raw
// s_barrier — never vmcnt(0) until the last iter. 4 waves in 2x2, wave tile
// 64x64 = 4x4 MFMAs per iter. Lean epilogue: bare exp2, NO masks (pad rows/
// cols are zero -> exp2(0)=1, exact constant subtracted in finalize).
// NOTE: all register-array subscripts COMPILE-TIME (R8: runtime idx -> 1.3 GB
// scratch spill). Frag layouts (16x16x32 bf16): A/B[row=l15][k=quad*8+j];
// C/D col=l15, row=quad*4+reg.  batch = blockIdx&7 -> XCD-pinned L2 set.
// ---------------------------------------------------------------------------
__global__ __launch_bounds__(256, 2)
void mfma_lse(const u16* __restrict__ des1, const u16* __restrict__ des2,
              float* __restrict__ row_sum, float* __restrict__ col_sum,
              float* __restrict__ diag, int M) {
  __shared__ __align__(16) u16 bufA[2][4096];   // 8 KB each
  __shared__ __align__(16) u16 bufB[2][4096];

  const int flat = blockIdx.x;
  const int b = flat & 7;
  const int f = flat >> 3;
  const int mt = f % NRB;
  const int nt = (f / NRB + mt) % NRB;          // stagger col-atomic order
  const int m0 = mt * 128, n0 = nt * 128;
  const int t = threadIdx.x;
  const int w = t >> 6, lane = t & 63;
  const int wm = w >> 1, wn = w & 1;
  const int quad = lane >> 4, l15 = lane & 15;

  auto stage = [&](int kb, int sel) {
    const u16* Ak = des1 + (((size_t)b * NKB + kb) * NRB + mt) * 4096;
    const u16* Bk = des2 + (((size_t)b * NKB + kb) * NRB + nt) * 4096;
#pragma unroll
    for (int i = 0; i < 2; ++i) {
      int idx = i * 256 + t;
      gld16(Ak + (size_t)idx * 8, &bufA[sel][idx * 8]);
      gld16(Bk + (size_t)idx * 8, &bufB[sel][idx * 8]);
    }
  };

  f32x4 acc[4][4] = {};

  stage(0, 0);
  for (int kb = 0; kb < NKB; ++kb) {
    if (kb + 1 < NKB) {
      stage(kb + 1, (kb + 1) & 1);
      asm volatile("s_waitcnt vmcnt(4)" ::: "memory");   // kb's tile resident
    } else {
      asm volatile("s_waitcnt vmcnt(0)" ::: "memory");
    }
    asm volatile("s_barrier" ::: "memory");

    const u16* As = bufA[kb & 1];
    const u16* Bs = bufB[kb & 1];
    bf16x8 af[4], bf[4];
#pragma unroll
    for (int i = 0; i < 4; ++i) {
      int row = wm * 64 + i * 16 + l15;
      int slot = quad ^ ((row >> 1) & 3);
      af[i] = *(const bf16x8*)&As[(row * 4 + slot) * 8];
    }
#pragma unroll
    for (int j = 0; j < 4; ++j) {
      int row = wn * 64 + j * 16 + l15;
      int slot = quad ^ ((row >> 1) & 3);
      bf[j] = *(const bf16x8*)&Bs[(row * 4 + slot) * 8];
    }
#pragma unroll
    for (int i = 0; i < 4; ++i)
#pragma unroll
      for (int j = 0; j < 4; ++j)
        acc[i][j] = __builtin_amdgcn_mfma_f32_16x16x32_bf16(
            af[i], bf[j], acc[i][j], 0, 0, 0);

    asm volatile("s_waitcnt lgkmcnt(0)" ::: "memory");   // frag reads done
    asm volatile("s_barrier" ::: "memory");              // before overwrite
  }

  // ---- lean epilogue: bare exp2, no masks, shuffle-reduced atomics ----
  float cp[4] = {0.f, 0.f, 0.f, 0.f};
#pragma unroll
  for (int i = 0; i < 4; ++i)
#pragma unroll
    for (int r = 0; r < 4; ++r) {
      float rv = 0.f;
#pragma unroll
      for (int j = 0; j < 4; ++j) {
        float e = exp2f(acc[i][j][r]);
        rv += e;
        cp[j] += e;
      }
      rv += __shfl_xor(rv, 1); rv += __shfl_xor(rv, 2);
      rv += __shfl_xor(rv, 4); rv += __shfl_xor(rv, 8);
      if (l15 == 0)
        atomicAdd(&row_sum[(size_t)b * MP + m0 + wm * 64 + i * 16 + quad * 4 + r], rv);
    }
#pragma unroll
  for (int j = 0; j < 4; ++j) {
    float c = cp[j];
    c += __shfl_xor(c, 16); c += __shfl_xor(c, 32);
    if (quad == 0)
      atomicAdd(&col_sum[(size_t)b * MP + n0 + wn * 64 + j * 16 + l15], c);
  }
  if (mt == nt && wm == wn) {
#pragma unroll
    for (int i = 0; i < 4; ++i)
#pragma unroll
      for (int r = 0; r < 4; ++r)
        if (l15 == quad * 4 + r)
          diag[(size_t)b * MP + m0 + wm * 64 + i * 16 + quad * 4 + r] =
              acc[i][i][r];
  }
}

// ---------------------------------------------------------------------------
// loss = mean over valid of log(rs - pad) + log(cs - pad) - 2*ln2*diag'
// pad = MP - M exact (pad rows/cols contributed exp2(0)=1 each).
// ---------------------------------------------------------------------------
__global__ __launch_bounds__(256)
void finalize(const float* __restrict__ row_sum, const float* __restrict__ col_sum,
              const float* __restrict__ diag, float* __restrict__ out,
              int M, float padf, float inv_total) {
  __shared__ float red[4];
  const int i = blockIdx.x * 256 + threadIdx.x;   // over NB*MP
  const int mm = i % MP;
  float s = 0.f;
  if (mm < M)
    s = __logf(row_sum[i] - padf) + __logf(col_sum[i] - padf) - LN2X2 * diag[i];
#pragma unroll
  for (int o = 1; o < 64; o <<= 1) s += __shfl_xor(s, o);
  const int lane = threadIdx.x & 63, wid = threadIdx.x >> 6;
  if (lane == 0) red[wid] = s;
  __syncthreads();
  if (threadIdx.x == 0)
    atomicAdd(out, (red[0] + red[1] + red[2] + red[3]) * inv_total);
}

extern "C" void kernel_launch(void* const* d_in, const int* in_sizes, int n_in,
                              void* d_out, int out_size, void* d_ws, size_t ws_size,
                              hipStream_t stream) {
  const float* p1 = (const float*)d_in[0];
  const float* p2 = (const float*)d_in[1];
  const int* y1 = (const int*)d_in[2];
  const int* x1 = (const int*)d_in[3];
  const int* y2 = (const int*)d_in[4];
  const int* x2 = (const int*)d_in[5];
  const int M = in_sizes[2];                    // 3540 (<= MP)

  float* row_sum = (float*)d_ws;                // NB*MP
  float* col_sum = row_sum + (size_t)NB * MP;   // NB*MP
  float* diagbuf = col_sum + (size_t)NB * MP;   // NB*MP
  size_t off = (((size_t)3 * NB * MP * sizeof(float)) + 255) & ~(size_t)255;
  u16* des1 = (u16*)((char*)d_ws + off);        // NB*MP*NC bf16, tiled+swizzled
  u16* des2 = des1 + (size_t)NB * MP * NC;

  hipMemsetAsync(d_ws, 0, (size_t)2 * NB * MP * sizeof(float), stream);
  hipMemsetAsync(d_out, 0, sizeof(float), stream);

  dim3 ggrid(MP / 64, 8, 2 * NB);               // (56, 8, 16)
  gather_kernel<<<ggrid, 256, 0, stream>>>(p1, p2, y1, x1, y2, x2, des1, des2, M);

  mfma_lse<<<dim3(NB * NRB * NRB), 256, 0, stream>>>(des1, des2, row_sum,
                                                     col_sum, diagbuf, M);

  finalize<<<(NB * MP) / 256, 256, 0, stream>>>(row_sum, col_sum, diagbuf,
                                                (float*)d_out, M,
                                                (float)(MP - M),
                                                1.f / (float)(NB * M));
}